// Round 2
// baseline (8912.208 us; speedup 1.0000x reference)
//
#include <hip/hip_runtime.h>
#include <hip/hip_bf16.h>
#include <cmath>

#define B_    2
#define T_    1024
#define BT_   2048
#define C_    1024
#define H_    16
#define D_    64
#define NH_   4096
#define E_    2
#define CH_   512          // MoE token chunk
#define WIN_  256

// ---------------- LayerNorm (ddof=1) ----------------
__global__ __launch_bounds__(256) void ln_kernel(
    const float* __restrict__ x, const float* __restrict__ g,
    const float* __restrict__ b, float* __restrict__ out)
{
    int row = blockIdx.x;           // token
    int tid = threadIdx.x;
    __shared__ float rs[256], rq[256];
    const float* xp = x + (size_t)row * C_;
    float s = 0.f, q = 0.f;
    for (int c = tid; c < C_; c += 256) {
        float v = xp[c];
        s += v; q += v * v;
    }
    rs[tid] = s; rq[tid] = q; __syncthreads();
    for (int off = 128; off > 0; off >>= 1) {
        if (tid < off) { rs[tid] += rs[tid+off]; rq[tid] += rq[tid+off]; }
        __syncthreads();
    }
    float mean = rs[0] * (1.f / C_);
    float var  = (rq[0] - (float)C_ * mean * mean) * (1.f / (C_ - 1));
    float inv  = rsqrtf(var + 1e-5f);
    for (int c = tid; c < C_; c += 256)
        out[(size_t)row * C_ + c] = (xp[c] - mean) * inv * g[c] + b[c];
}

// ---------------- weight prep ----------------
// W[h][c][d] (16,1024,64) -> Wt[c][h*64+d]
__global__ __launch_bounds__(256) void prep_whcd_kernel(
    const float* __restrict__ W, float* __restrict__ Wt)
{
    int idx = blockIdx.x * 256 + threadIdx.x;     // < C_*C_
    int c = idx >> 10, hd = idx & 1023;
    int h = hd >> 6, d = hd & 63;
    Wt[idx] = W[((size_t)h * C_ + c) * D_ + d];
}

// Wq[h][q][c][d] summed over q -> Wt[c][h*64+d]
__global__ __launch_bounds__(256) void prep_wq_kernel(
    const float* __restrict__ Wq, float* __restrict__ Wt)
{
    int idx = blockIdx.x * 256 + threadIdx.x;
    int c = idx >> 10, hd = idx & 1023;
    int h = hd >> 6, d = hd & 63;
    size_t i0 = (((size_t)h * 2 + 0) * C_ + c) * D_ + d;
    size_t i1 = (((size_t)h * 2 + 1) * C_ + c) * D_ + d;
    Wt[idx] = Wq[i0] + Wq[i1];
}

// ---------------- generic GEMM: Cout = A @ B (+bias)(+res), f32 ----------------
template <bool BIAS, bool RES>
__global__ __launch_bounds__(256) void gemm_kernel(
    const float* __restrict__ A, const float* __restrict__ B,
    const float* __restrict__ bias, const float* __restrict__ res,
    float* __restrict__ Cout, int M, int N, int K)
{
    __shared__ float As[64][17];
    __shared__ float Bs[16][65];
    int tid = threadIdx.x;
    int tx = tid & 15, ty = tid >> 4;
    int row0 = blockIdx.y * 64;
    int col0 = blockIdx.x * 64;
    float acc[4][4] = {};
    for (int k0 = 0; k0 < K; k0 += 16) {
        #pragma unroll
        for (int l = 0; l < 4; ++l) {
            int idx = l * 256 + tid;
            int r = idx >> 4, c = idx & 15;
            As[r][c] = A[(size_t)(row0 + r) * K + k0 + c];
        }
        #pragma unroll
        for (int l = 0; l < 4; ++l) {
            int idx = l * 256 + tid;
            int r = idx >> 6, c = idx & 63;
            Bs[r][c] = B[(size_t)(k0 + r) * N + col0 + c];
        }
        __syncthreads();
        #pragma unroll
        for (int kk = 0; kk < 16; ++kk) {
            float a[4], bb[4];
            #pragma unroll
            for (int i = 0; i < 4; ++i) a[i] = As[ty + 16*i][kk];
            #pragma unroll
            for (int j = 0; j < 4; ++j) bb[j] = Bs[kk][tx + 16*j];
            #pragma unroll
            for (int i = 0; i < 4; ++i)
                #pragma unroll
                for (int j = 0; j < 4; ++j)
                    acc[i][j] += a[i] * bb[j];
        }
        __syncthreads();
    }
    #pragma unroll
    for (int i = 0; i < 4; ++i) {
        int r = row0 + ty + 16*i;
        #pragma unroll
        for (int j = 0; j < 4; ++j) {
            int c = col0 + tx + 16*j;
            float v = acc[i][j];
            if (BIAS) v += bias[c];
            if (RES)  v += res[(size_t)r * N + c];
            Cout[(size_t)r * N + c] = v;
        }
    }
}

// ---------------- dual GEMM: P = swish(A@Bs + bs; beta) * (A@Bg + bg) ----------------
__global__ __launch_bounds__(256) void gemm_dual_kernel(
    const float* __restrict__ A, const float* __restrict__ Bsw,
    const float* __restrict__ Bgl, const float* __restrict__ bs,
    const float* __restrict__ bg, const float* __restrict__ beta_all, int e,
    float* __restrict__ P, int M, int N, int K)
{
    __shared__ float As[64][17];
    __shared__ float S1[16][65];
    __shared__ float S2[16][65];
    int tid = threadIdx.x;
    int tx = tid & 15, ty = tid >> 4;
    int row0 = blockIdx.y * 64;
    int col0 = blockIdx.x * 64;
    float acc1[4][4] = {};
    float acc2[4][4] = {};
    for (int k0 = 0; k0 < K; k0 += 16) {
        #pragma unroll
        for (int l = 0; l < 4; ++l) {
            int idx = l * 256 + tid;
            int r = idx >> 4, c = idx & 15;
            As[r][c] = A[(size_t)(row0 + r) * K + k0 + c];
        }
        #pragma unroll
        for (int l = 0; l < 4; ++l) {
            int idx = l * 256 + tid;
            int r = idx >> 6, c = idx & 63;
            S1[r][c] = Bsw[(size_t)(k0 + r) * N + col0 + c];
            S2[r][c] = Bgl[(size_t)(k0 + r) * N + col0 + c];
        }
        __syncthreads();
        #pragma unroll
        for (int kk = 0; kk < 16; ++kk) {
            float a[4], b1[4], b2[4];
            #pragma unroll
            for (int i = 0; i < 4; ++i) a[i] = As[ty + 16*i][kk];
            #pragma unroll
            for (int j = 0; j < 4; ++j) { b1[j] = S1[kk][tx + 16*j]; b2[j] = S2[kk][tx + 16*j]; }
            #pragma unroll
            for (int i = 0; i < 4; ++i)
                #pragma unroll
                for (int j = 0; j < 4; ++j) {
                    acc1[i][j] += a[i] * b1[j];
                    acc2[i][j] += a[i] * b2[j];
                }
        }
        __syncthreads();
    }
    float beta = beta_all[e];
    #pragma unroll
    for (int i = 0; i < 4; ++i) {
        int r = row0 + ty + 16*i;
        #pragma unroll
        for (int j = 0; j < 4; ++j) {
            int c = col0 + tx + 16*j;
            float sx = acc1[i][j] + bs[c];
            float gl = acc2[i][j] + bg[c];
            float sw = sx / (1.f + expf(-beta * sx));
            P[(size_t)r * N + c] = sw * gl;
        }
    }
}

// ---------------- attention: per (h,b,t) block ----------------
// Qb/Kb/Vb layout: [b*T + t][h*64 + d]
__global__ __launch_bounds__(256) void attn_kernel(
    const float* __restrict__ Qb, const float* __restrict__ Kb,
    const float* __restrict__ Vb, float* __restrict__ Ob)
{
    int bid = blockIdx.x;
    int t = bid & (T_ - 1);
    int b = (bid >> 10) & (B_ - 1);
    int h = bid >> 11;
    int tid = threadIdx.x;
    __shared__ float q[64];
    __shared__ float sc[T_];
    __shared__ float red[256];

    if (tid < 64) q[tid] = Qb[(size_t)(b * T_ + t) * C_ + h * 64 + tid];
    __syncthreads();

    // scores with reinterpret-reshape: kr[d][s] = k[d*16 + (s>>6)][s&63]
    for (int cc = 0; cc < 4; ++cc) {
        int s = cc * 256 + tid;
        const float* kp = Kb + (size_t)(b * T_ + (s >> 6)) * C_ + h * 64 + (s & 63);
        float acc = 0.f;
        #pragma unroll
        for (int d = 0; d < 64; ++d) acc += q[d] * kp[(size_t)d * 16 * C_];
        float v = acc * 0.125f;                 // D^-0.5
        if (s <= t - WIN_) v = -INFINITY;       // past-window mask only (no causal mask)
        sc[s] = v;
    }
    __syncthreads();

    // softmax over s
    float mx = -INFINITY;
    for (int cc = 0; cc < 4; ++cc) mx = fmaxf(mx, sc[cc * 256 + tid]);
    red[tid] = mx; __syncthreads();
    for (int off = 128; off > 0; off >>= 1) {
        if (tid < off) red[tid] = fmaxf(red[tid], red[tid + off]);
        __syncthreads();
    }
    mx = red[0];
    __syncthreads();
    float sum = 0.f;
    for (int cc = 0; cc < 4; ++cc) {
        int s = cc * 256 + tid;
        float e = expf(sc[s] - mx);
        sc[s] = e; sum += e;
    }
    __syncthreads();
    red[tid] = sum; __syncthreads();
    for (int off = 128; off > 0; off >>= 1) {
        if (tid < off) red[tid] += red[tid + off];
        __syncthreads();
    }
    float denom = red[0];
    __syncthreads();

    // o[t,d] = sum_s w[s] * V[s,d]
    int d = tid & 63, part = tid >> 6;
    const float* vp = Vb + (size_t)(b * T_ + part * 256) * C_ + h * 64 + d;
    float acc = 0.f;
    for (int s = 0; s < 256; ++s) acc += sc[part * 256 + s] * vp[(size_t)s * C_];
    red[tid] = acc; __syncthreads();
    if (tid < 64) {
        float o = (red[tid] + red[tid + 64] + red[tid + 128] + red[tid + 192]) / denom;
        Ob[(size_t)(b * T_ + t) * C_ + h * 64 + tid] = o;
    }
}

// ---------------- router: logits, max, argmax ----------------
__global__ __launch_bounds__(256) void router_kernel(
    const float* __restrict__ xn2, const float* __restrict__ Wg,
    const float* __restrict__ bgp, float* __restrict__ mOut,
    int* __restrict__ topiOut)
{
    int g = blockIdx.x;
    int tid = threadIdx.x;
    __shared__ float r0[256], r1[256];
    const float* xp = xn2 + (size_t)g * C_;
    float a0 = 0.f, a1 = 0.f;
    for (int c = tid; c < C_; c += 256) {
        float xv = xp[c];
        a0 += xv * Wg[c * 2 + 0];
        a1 += xv * Wg[c * 2 + 1];
    }
    r0[tid] = a0; r1[tid] = a1; __syncthreads();
    for (int off = 128; off > 0; off >>= 1) {
        if (tid < off) { r0[tid] += r0[tid+off]; r1[tid] += r1[tid+off]; }
        __syncthreads();
    }
    if (tid == 0) {
        float l0 = r0[0] + bgp[0];
        float l1 = r1[0] + bgp[1];
        topiOut[g] = (l1 > l0) ? 1 : 0;
        mOut[g] = fmaxf(l0, l1);
    }
}

// ---------------- softmax of max-logit over TOKEN axis (faithful bug) ----------------
__global__ __launch_bounds__(256) void batch_softmax_kernel(
    const float* __restrict__ m, float* __restrict__ topw)
{
    int b = blockIdx.x;
    int tid = threadIdx.x;
    __shared__ float red[256];
    const float* mp = m + (size_t)b * T_;
    float mx = -INFINITY;
    for (int t = tid; t < T_; t += 256) mx = fmaxf(mx, mp[t]);
    red[tid] = mx; __syncthreads();
    for (int off = 128; off > 0; off >>= 1) {
        if (tid < off) red[tid] = fmaxf(red[tid], red[tid+off]);
        __syncthreads();
    }
    mx = red[0]; __syncthreads();
    float s = 0.f;
    for (int t = tid; t < T_; t += 256) s += expf(mp[t] - mx);
    red[tid] = s; __syncthreads();
    for (int off = 128; off > 0; off >>= 1) {
        if (tid < off) red[tid] += red[tid+off];
        __syncthreads();
    }
    float denom = red[0];
    for (int t = tid; t < T_; t += 256)
        topw[(size_t)b * T_ + t] = expf(mp[t] - mx) / denom;
}

// ---------------- final mix: out = x1 + topw * eout[topi] ----------------
__global__ __launch_bounds__(256) void mix_kernel(
    const float* __restrict__ x1, const float* __restrict__ eout,
    const float* __restrict__ topw, const int* __restrict__ topi,
    float* __restrict__ out, int tok0)
{
    int idx = blockIdx.x * 256 + threadIdx.x;   // CH_*C_ elements
    int i = idx >> 10;          // local token
    int c = idx & 1023;
    int g = tok0 + i;           // global token
    int e = topi[g];
    float w = topw[g];
    out[(size_t)g * C_ + c] =
        x1[(size_t)g * C_ + c] + w * eout[(size_t)e * CH_ * C_ + (size_t)i * C_ + c];
}

// ---------------- host ----------------
extern "C" void kernel_launch(void* const* d_in, const int* in_sizes, int n_in,
                              void* d_out, int out_size, void* d_ws, size_t ws_size,
                              hipStream_t stream)
{
    const float* x    = (const float*)d_in[0];
    const float* Wq   = (const float*)d_in[1];
    const float* Wk   = (const float*)d_in[2];
    const float* Wv   = (const float*)d_in[3];
    const float* Wp   = (const float*)d_in[4];
    const float* bp   = (const float*)d_in[5];
    const float* ln1g = (const float*)d_in[6];
    const float* ln1b = (const float*)d_in[7];
    const float* ln2g = (const float*)d_in[8];
    const float* ln2b = (const float*)d_in[9];
    const float* Wg   = (const float*)d_in[10];
    const float* bg   = (const float*)d_in[11];
    const float* Ew1  = (const float*)d_in[12];
    const float* Eb1  = (const float*)d_in[13];
    const float* Ews  = (const float*)d_in[14];
    const float* Ebs  = (const float*)d_in[15];
    const float* Ebeta= (const float*)d_in[16];
    const float* Ewg  = (const float*)d_in[17];
    const float* Ebg  = (const float*)d_in[18];
    const float* Ew2  = (const float*)d_in[19];
    const float* Eb2  = (const float*)d_in[20];
    float* out = (float*)d_out;

    const size_t M1 = 1024 * 1024;   // 1M floats
    float* ws = (float*)d_ws;
    // Phase A layout (attention). Phase B (MoE) aliases the dead region [0, 13M).
    float* xn   = ws;                 // [0, 2M)
    float* wqsT = ws + 2 * M1;        // [2M, 3M)
    float* wkT  = ws + 3 * M1;        // [3M, 4M)
    float* wvT  = ws + 4 * M1;        // [4M, 5M)
    float* Qb   = ws + 5 * M1;        // [5M, 7M)
    float* Kb   = ws + 7 * M1;        // [7M, 9M)
    float* Vb   = ws + 9 * M1;        // [9M, 11M)
    float* Ob   = ws + 11 * M1;       // [11M, 13M)
    float* x1   = ws + 13 * M1;       // [13M, 15M)
    float* xn2  = ws + 15 * M1;       // [15M, 17M)
    float* mbuf = ws + 17 * M1;       // BT
    float* topw = mbuf + BT_;         // BT
    int*   topi = (int*)(topw + BT_); // BT
    // Phase B aliases (per-chunk MoE scratch):
    float* h1   = ws;                 // [0, 4M)   E*CH*NH
    float* pbuf = ws + 4 * M1;        // [4M, 8M)  E*CH*NH
    float* eout = ws + 8 * M1;        // [8M, 9M)  E*CH*C

    // 1. LN1
    ln_kernel<<<BT_, 256, 0, stream>>>(x, ln1g, ln1b, xn);
    // 2. weight prep
    prep_whcd_kernel<<<C_*C_/256, 256, 0, stream>>>(Wk, wkT);
    prep_whcd_kernel<<<C_*C_/256, 256, 0, stream>>>(Wv, wvT);
    prep_wq_kernel  <<<C_*C_/256, 256, 0, stream>>>(Wq, wqsT);
    // 3. Q/K/V projections: [BT,C] @ [C,C]
    {
        dim3 grid(C_/64, BT_/64);
        gemm_kernel<false,false><<<grid, 256, 0, stream>>>(xn, wqsT, nullptr, nullptr, Qb, BT_, C_, C_);
        gemm_kernel<false,false><<<grid, 256, 0, stream>>>(xn, wkT,  nullptr, nullptr, Kb, BT_, C_, C_);
        gemm_kernel<false,false><<<grid, 256, 0, stream>>>(xn, wvT,  nullptr, nullptr, Vb, BT_, C_, C_);
    }
    // 4. attention
    attn_kernel<<<H_*B_*T_, 256, 0, stream>>>(Qb, Kb, Vb, Ob);
    // 5. out proj + residual: x1 = x + Ob @ Wp + bp
    {
        dim3 grid(C_/64, BT_/64);
        gemm_kernel<true,true><<<grid, 256, 0, stream>>>(Ob, Wp, bp, x, x1, BT_, C_, C_);
    }
    // 6. LN2
    ln_kernel<<<BT_, 256, 0, stream>>>(x1, ln2g, ln2b, xn2);
    // 7. router
    router_kernel<<<BT_, 256, 0, stream>>>(xn2, Wg, bg, mbuf, topi);
    batch_softmax_kernel<<<B_, 256, 0, stream>>>(mbuf, topw);
    // 8. MoE dense, chunked (aliases the attention scratch — xn/weights/Q/K dead by now)
    for (int chunk = 0; chunk < BT_/CH_; ++chunk) {
        const float* A0 = xn2 + (size_t)chunk * CH_ * C_;
        for (int e = 0; e < E_; ++e) {
            float* h1e = h1   + (size_t)e * CH_ * NH_;
            float* pe  = pbuf + (size_t)e * CH_ * NH_;
            float* ee  = eout + (size_t)e * CH_ * C_;
            {   // h1 = xn2 @ Ew1[e] + Eb1[e]   (M=CH, K=C, N=NH)
                dim3 grid(NH_/64, CH_/64);
                gemm_kernel<true,false><<<grid, 256, 0, stream>>>(
                    A0, Ew1 + (size_t)e * C_ * NH_, Eb1 + (size_t)e * NH_, nullptr,
                    h1e, CH_, NH_, C_);
            }
            {   // p = swish(h1@Ews+Ebs)*(h1@Ewg+Ebg)   (M=CH, K=NH, N=NH)
                dim3 grid(NH_/64, CH_/64);
                gemm_dual_kernel<<<grid, 256, 0, stream>>>(
                    h1e, Ews + (size_t)e * NH_ * NH_, Ewg + (size_t)e * NH_ * NH_,
                    Ebs + (size_t)e * NH_, Ebg + (size_t)e * NH_, Ebeta, e,
                    pe, CH_, NH_, NH_);
            }
            {   // eout = p @ Ew2[e] + Eb2[e]   (M=CH, K=NH, N=C)
                dim3 grid(C_/64, CH_/64);
                gemm_kernel<true,false><<<grid, 256, 0, stream>>>(
                    pe, Ew2 + (size_t)e * NH_ * C_, Eb2 + (size_t)e * C_, nullptr,
                    ee, CH_, C_, NH_);
            }
        }
        mix_kernel<<<CH_*C_/256, 256, 0, stream>>>(x1, eout, topw, topi, out, chunk * CH_);
    }
}

// Round 3
// 1637.405 us; speedup vs baseline: 5.4429x; 5.4429x over previous
//
#include <hip/hip_runtime.h>
#include <hip/hip_bf16.h>
#include <cmath>

#define B_    2
#define T_    1024
#define BT_   2048
#define C_    1024
#define H_    16
#define NH_   4096
#define E_    2
#define WIN_  256
#define G_    4          // attention hb-chunk size

typedef unsigned short u16;
typedef __attribute__((ext_vector_type(8))) short short8;
typedef __attribute__((ext_vector_type(4))) float f32x4;

__device__ __forceinline__ u16 f2b(float f) {
    __hip_bfloat16 h = __float2bfloat16(f);
    return *(u16*)&h;
}
__device__ __forceinline__ float b2f(u16 u) {
    __hip_bfloat16 h; *(u16*)&h = u;
    return __bfloat162float(h);
}

// ============================================================================
// MFMA GEMM, TN path: A bf16 [M][K] (lda), B bf16 [N][K] (ldb).
// TILE: 128 x (TNJ*32). 4 waves in 2x2. Batched via z with offset coefs.
// EPI: 0=f32, 1=bf16, 2=scores(scale+window-mask,f32), 3=x1(bias+res,f32)
// ============================================================================
template<int TNJ, int EPI>
__global__ __launch_bounds__(256) void gemm_tn(
    const u16* __restrict__ A, const u16* __restrict__ B,
    float* __restrict__ Cf, u16* __restrict__ Cb,
    const float* __restrict__ bias, const float* __restrict__ res,
    int K, int lda, int ldb, int ldc,
    int hb0, long aCz, long aCb, long aCh,
    long bCb, long bCh, long cCz, long cCb, long cCh)
{
    constexpr int TN = TNJ * 32;
    __shared__ u16 As[128][40];
    __shared__ u16 Bs[TN][40];
    int tid = threadIdx.x;
    int z = blockIdx.z;
    int hb = hb0 + z;
    int hh = hb >> 1, bb = hb & 1;
    const u16* Ap = A + aCz * z + aCb * bb + aCh * hh + (size_t)blockIdx.y * 128 * lda;
    const u16* Bp = B + bCb * bb + bCh * hh + (size_t)blockIdx.x * TN * ldb;
    size_t cOff = (size_t)(cCz * z + cCb * bb + cCh * hh);

    f32x4 acc[4][TNJ];
    #pragma unroll
    for (int i = 0; i < 4; ++i)
        #pragma unroll
        for (int j = 0; j < TNJ; ++j)
            acc[i][j] = (f32x4){0.f, 0.f, 0.f, 0.f};

    int lane = tid & 63, w = tid >> 6;
    int wr = (w >> 1) * 64, wc = (w & 1) * (TNJ * 16);
    int fm = lane & 15, fk = (lane >> 4) * 8;

    for (int k0 = 0; k0 < K; k0 += 32) {
        {   // stage A: 128x32
            int r = tid >> 1, hf = (tid & 1) * 16;
            const u16* s = Ap + (size_t)r * lda + k0 + hf;
            *(float4*)&As[r][hf]     = *(const float4*)s;
            *(float4*)&As[r][hf + 8] = *(const float4*)(s + 8);
        }
        if (TN == 128) {  // stage B: 128x32
            int r = tid >> 1, hf = (tid & 1) * 16;
            const u16* s = Bp + (size_t)r * ldb + k0 + hf;
            *(float4*)&Bs[r][hf]     = *(const float4*)s;
            *(float4*)&Bs[r][hf + 8] = *(const float4*)(s + 8);
        } else {          // 64x32
            int r = tid >> 2, hf = (tid & 3) * 8;
            *(float4*)&Bs[r][hf] = *(const float4*)(Bp + (size_t)r * ldb + k0 + hf);
        }
        __syncthreads();
        short8 af[4], bf[TNJ];
        #pragma unroll
        for (int i = 0; i < 4; ++i) af[i] = *(const short8*)&As[wr + i * 16 + fm][fk];
        #pragma unroll
        for (int j = 0; j < TNJ; ++j) bf[j] = *(const short8*)&Bs[wc + j * 16 + fm][fk];
        #pragma unroll
        for (int i = 0; i < 4; ++i)
            #pragma unroll
            for (int j = 0; j < TNJ; ++j)
                acc[i][j] = __builtin_amdgcn_mfma_f32_16x16x32_bf16(af[i], bf[j], acc[i][j], 0, 0, 0);
        __syncthreads();
    }

    int rBase = blockIdx.y * 128 + wr + (lane >> 4) * 4;
    int cBase = blockIdx.x * TN + wc + fm;
    #pragma unroll
    for (int i = 0; i < 4; ++i)
        #pragma unroll
        for (int j = 0; j < TNJ; ++j)
            #pragma unroll
            for (int r = 0; r < 4; ++r) {
                int row = rBase + i * 16 + r;
                int col = cBase + j * 16;
                float v = acc[i][j][r];
                size_t o = cOff + (size_t)row * ldc + col;
                if (EPI == 0) Cf[o] = v;
                else if (EPI == 1) Cb[o] = f2b(v);
                else if (EPI == 2) {
                    v *= 0.125f;
                    if (col <= row - WIN_) v = -INFINITY;  // past-window mask only
                    Cf[o] = v;
                } else {  // X1: + bias + residual
                    Cf[o] = v + bias[col] + res[(size_t)row * ldc + col];
                }
            }
}

// ---- NT B staging: f32 [K][N] source -> LDS [n][k] bf16, k-rotation swizzle ----
__device__ __forceinline__ void stage_nt128(u16* dst, const float* src, int ldb, int tid) {
    int kp = tid >> 4;            // k-pair 0..15
    int noff = (tid & 15) * 8;
    const float* s0 = src + (size_t)(2 * kp) * ldb + noff;
    const float* s1 = s0 + ldb;
    float4 a0 = *(const float4*)s0, a1 = *(const float4*)(s0 + 4);
    float4 b0 = *(const float4*)s1, b1 = *(const float4*)(s1 + 4);
    float r0[8] = {a0.x, a0.y, a0.z, a0.w, a1.x, a1.y, a1.z, a1.w};
    float r1[8] = {b0.x, b0.y, b0.z, b0.w, b1.x, b1.y, b1.z, b1.w};
    #pragma unroll
    for (int i = 0; i < 8; ++i) {
        int n = noff + i;
        int kk = (2 * kp + 8 * ((n >> 3) & 3)) & 31;
        ushort2 t; t.x = f2b(r0[i]); t.y = f2b(r1[i]);
        *(ushort2*)(dst + n * 32 + kk) = t;
    }
}
__device__ __forceinline__ void stage_nt64(u16* dst, const float* src, int ldb, int tid) {
    int kp = tid >> 4;            // 0..15
    int noff = (tid & 15) * 4;
    const float* s0 = src + (size_t)(2 * kp) * ldb + noff;
    const float* s1 = s0 + ldb;
    float4 a = *(const float4*)s0;
    float4 b = *(const float4*)s1;
    float r0[4] = {a.x, a.y, a.z, a.w};
    float r1[4] = {b.x, b.y, b.z, b.w};
    #pragma unroll
    for (int i = 0; i < 4; ++i) {
        int n = noff + i;
        int kk = (2 * kp + 8 * ((n >> 3) & 3)) & 31;
        ushort2 t; t.x = f2b(r0[i]); t.y = f2b(r1[i]);
        *(ushort2*)(dst + n * 32 + kk) = t;
    }
}
__device__ __forceinline__ short8 fragB_nt(const u16* Bs, int n, int fk) {
    int kk = (fk + 8 * ((n >> 3) & 3)) & 31;
    return *(const short8*)(Bs + n * 32 + kk);
}

// ============================================================================
// MFMA GEMM, NT path: A bf16 [M][K], B f32 [K][N] converted in-kernel.
// EPI: 0 = bf16(acc+bias); 1 = MIX first (res + coef*(acc+bias) -> f32);
//      2 = MIX accum (Cf += coef*(acc+bias))
// ============================================================================
template<int TNJ, int EPI>
__global__ __launch_bounds__(256) void gemm_nt(
    const u16* __restrict__ A, const float* __restrict__ Bw,
    u16* __restrict__ Cb, float* __restrict__ Cf,
    const float* __restrict__ bias, const float* __restrict__ coef,
    const float* __restrict__ res,
    int K, int lda, int ldb, int ldc)
{
    constexpr int TN = TNJ * 32;
    __shared__ u16 As[128][40];
    __shared__ u16 Bs[TN * 32];
    int tid = threadIdx.x;
    const u16* Ap = A + (size_t)blockIdx.y * 128 * lda;
    const float* Bp = Bw + (size_t)blockIdx.x * TN;

    f32x4 acc[4][TNJ];
    #pragma unroll
    for (int i = 0; i < 4; ++i)
        #pragma unroll
        for (int j = 0; j < TNJ; ++j)
            acc[i][j] = (f32x4){0.f, 0.f, 0.f, 0.f};

    int lane = tid & 63, w = tid >> 6;
    int wr = (w >> 1) * 64, wc = (w & 1) * (TNJ * 16);
    int fm = lane & 15, fk = (lane >> 4) * 8;

    for (int k0 = 0; k0 < K; k0 += 32) {
        {   int r = tid >> 1, hf = (tid & 1) * 16;
            const u16* s = Ap + (size_t)r * lda + k0 + hf;
            *(float4*)&As[r][hf]     = *(const float4*)s;
            *(float4*)&As[r][hf + 8] = *(const float4*)(s + 8);
        }
        if (TN == 128) stage_nt128(Bs, Bp + (size_t)k0 * ldb, ldb, tid);
        else           stage_nt64 (Bs, Bp + (size_t)k0 * ldb, ldb, tid);
        __syncthreads();
        short8 af[4], bf[TNJ];
        #pragma unroll
        for (int i = 0; i < 4; ++i) af[i] = *(const short8*)&As[wr + i * 16 + fm][fk];
        #pragma unroll
        for (int j = 0; j < TNJ; ++j) bf[j] = fragB_nt(Bs, wc + j * 16 + fm, fk);
        #pragma unroll
        for (int i = 0; i < 4; ++i)
            #pragma unroll
            for (int j = 0; j < TNJ; ++j)
                acc[i][j] = __builtin_amdgcn_mfma_f32_16x16x32_bf16(af[i], bf[j], acc[i][j], 0, 0, 0);
        __syncthreads();
    }

    int rBase = blockIdx.y * 128 + wr + (lane >> 4) * 4;
    int cBase = blockIdx.x * TN + wc + fm;
    #pragma unroll
    for (int i = 0; i < 4; ++i)
        #pragma unroll
        for (int j = 0; j < TNJ; ++j)
            #pragma unroll
            for (int r = 0; r < 4; ++r) {
                int row = rBase + i * 16 + r;
                int col = cBase + j * 16;
                float v = acc[i][j][r] ;
                size_t o = (size_t)row * ldc + col;
                if (EPI == 0) Cb[o] = f2b(v + bias[col]);
                else if (EPI == 1) Cf[o] = res[o] + coef[row] * (v + bias[col]);
                else Cf[o] += coef[row] * (v + bias[col]);
            }
}

// ============================================================================
// Dual NT GEMM: p = swish(A@B1 + bs; beta) * (A@B2 + bg), bf16 out. TILE_N=64.
// ============================================================================
__global__ __launch_bounds__(256) void gemm_nt_dual(
    const u16* __restrict__ A, const float* __restrict__ B1,
    const float* __restrict__ B2, const float* __restrict__ bs,
    const float* __restrict__ bg, const float* __restrict__ betaP,
    u16* __restrict__ P, int K, int lda, int ldb, int ldc)
{
    __shared__ u16 As[128][40];
    __shared__ u16 B1s[64 * 32];
    __shared__ u16 B2s[64 * 32];
    int tid = threadIdx.x;
    const u16* Ap = A + (size_t)blockIdx.y * 128 * lda;
    const float* B1p = B1 + (size_t)blockIdx.x * 64;
    const float* B2p = B2 + (size_t)blockIdx.x * 64;

    f32x4 a1[4][2], a2[4][2];
    #pragma unroll
    for (int i = 0; i < 4; ++i)
        #pragma unroll
        for (int j = 0; j < 2; ++j) {
            a1[i][j] = (f32x4){0.f, 0.f, 0.f, 0.f};
            a2[i][j] = (f32x4){0.f, 0.f, 0.f, 0.f};
        }

    int lane = tid & 63, w = tid >> 6;
    int wr = (w >> 1) * 64, wc = (w & 1) * 32;
    int fm = lane & 15, fk = (lane >> 4) * 8;

    for (int k0 = 0; k0 < K; k0 += 32) {
        {   int r = tid >> 1, hf = (tid & 1) * 16;
            const u16* s = Ap + (size_t)r * lda + k0 + hf;
            *(float4*)&As[r][hf]     = *(const float4*)s;
            *(float4*)&As[r][hf + 8] = *(const float4*)(s + 8);
        }
        stage_nt64(B1s, B1p + (size_t)k0 * ldb, ldb, tid);
        stage_nt64(B2s, B2p + (size_t)k0 * ldb, ldb, tid);
        __syncthreads();
        short8 af[4], b1f[2], b2f[2];
        #pragma unroll
        for (int i = 0; i < 4; ++i) af[i] = *(const short8*)&As[wr + i * 16 + fm][fk];
        #pragma unroll
        for (int j = 0; j < 2; ++j) {
            b1f[j] = fragB_nt(B1s, wc + j * 16 + fm, fk);
            b2f[j] = fragB_nt(B2s, wc + j * 16 + fm, fk);
        }
        #pragma unroll
        for (int i = 0; i < 4; ++i)
            #pragma unroll
            for (int j = 0; j < 2; ++j) {
                a1[i][j] = __builtin_amdgcn_mfma_f32_16x16x32_bf16(af[i], b1f[j], a1[i][j], 0, 0, 0);
                a2[i][j] = __builtin_amdgcn_mfma_f32_16x16x32_bf16(af[i], b2f[j], a2[i][j], 0, 0, 0);
            }
        __syncthreads();
    }

    float beta = betaP[0];
    int rBase = blockIdx.y * 128 + wr + (lane >> 4) * 4;
    int cBase = blockIdx.x * 64 + wc + fm;
    #pragma unroll
    for (int i = 0; i < 4; ++i)
        #pragma unroll
        for (int j = 0; j < 2; ++j)
            #pragma unroll
            for (int r = 0; r < 4; ++r) {
                int row = rBase + i * 16 + r;
                int col = cBase + j * 16;
                float sx = a1[i][j][r] + bs[col];
                float gl = a2[i][j][r] + bg[col];
                float sw = sx / (1.f + expf(-beta * sx));
                P[(size_t)row * ldc + col] = f2b(sw * gl);
            }
}

// ============================================================================
// Small kernels
// ============================================================================
// LayerNorm (ddof=1): out bf16 always; optional f32 copy.
__global__ __launch_bounds__(256) void ln_kernel(
    const float* __restrict__ x, const float* __restrict__ g,
    const float* __restrict__ b, u16* __restrict__ outB,
    float* __restrict__ outF, int wantF)
{
    int row = blockIdx.x;
    int tid = threadIdx.x;
    __shared__ float rs[256], rq[256];
    const float* xp = x + (size_t)row * C_;
    float s = 0.f, q = 0.f;
    for (int c = tid; c < C_; c += 256) {
        float v = xp[c];
        s += v; q += v * v;
    }
    rs[tid] = s; rq[tid] = q; __syncthreads();
    for (int off = 128; off > 0; off >>= 1) {
        if (tid < off) { rs[tid] += rs[tid + off]; rq[tid] += rq[tid + off]; }
        __syncthreads();
    }
    float mean = rs[0] * (1.f / C_);
    float var  = (rq[0] - (float)C_ * mean * mean) * (1.f / (C_ - 1));
    float inv  = rsqrtf(var + 1e-5f);
    for (int c = tid; c < C_; c += 256) {
        float v = (xp[c] - mean) * inv * g[c] + b[c];
        outB[(size_t)row * C_ + c] = f2b(v);
        if (wantF) outF[(size_t)row * C_ + c] = v;
    }
}

// Wk/Wv: f32 [H][C][D] -> bf16 [hd][c]
__global__ __launch_bounds__(256) void prep_whcd(const float* __restrict__ W, u16* __restrict__ out) {
    int idx = blockIdx.x * 256 + threadIdx.x;
    int hd = idx >> 10, c = idx & 1023;
    out[idx] = f2b(W[((size_t)(hd >> 6) * C_ + c) * 64 + (hd & 63)]);
}
// Wq summed over q: f32 [H][2][C][D] -> bf16 [hd][c]
__global__ __launch_bounds__(256) void prep_wq(const float* __restrict__ W, u16* __restrict__ out) {
    int idx = blockIdx.x * 256 + threadIdx.x;
    int hd = idx >> 10, c = idx & 1023;
    int h = hd >> 6, d = hd & 63;
    size_t i0 = (((size_t)h * 2 + 0) * C_ + c) * 64 + d;
    size_t i1 = (((size_t)h * 2 + 1) * C_ + c) * 64 + d;
    out[idx] = f2b(W[i0] + W[i1]);
}
// Wp: f32 [K][N] -> bf16 [N][K]
__global__ __launch_bounds__(256) void prep_wp(const float* __restrict__ W, u16* __restrict__ out) {
    int idx = blockIdx.x * 256 + threadIdx.x;
    int n = idx >> 10, k = idx & 1023;
    out[idx] = f2b(W[(size_t)k * C_ + n]);
}
// KrT[hb][s][d] = Kbf[(b*1024 + d*16 + (s>>6))*1024 + h*64 + (s&63)]
__global__ __launch_bounds__(256) void prep_krt(const u16* __restrict__ Kbf, u16* __restrict__ out) {
    int idx = blockIdx.x * 256 + threadIdx.x;
    int hb = idx >> 16, rem = idx & 65535;
    int s = rem >> 6, d = rem & 63;
    int h = hb >> 1, b = hb & 1;
    out[idx] = Kbf[((size_t)(b * 1024 + d * 16 + (s >> 6))) * 1024 + h * 64 + (s & 63)];
}
// VT[hb][d][s] = Vbf[(b*1024+s)*1024 + h*64 + d]
__global__ __launch_bounds__(256) void prep_vt(const u16* __restrict__ Vbf, u16* __restrict__ out) {
    int idx = blockIdx.x * 256 + threadIdx.x;
    int hb = idx >> 16, rem = idx & 65535;
    int d = rem >> 10, s = rem & 1023;
    int h = hb >> 1, b = hb & 1;
    out[idx] = Vbf[((size_t)(b * 1024 + s)) * 1024 + h * 64 + d];
}

// Row softmax over 1024 f32, in-place write as bf16 into row start.
__global__ __launch_bounds__(256) void softmax_rows(float* __restrict__ sc) {
    float* rp = sc + (size_t)blockIdx.x * 1024;
    int tid = threadIdx.x;
    float4 v = *(float4*)(rp + tid * 4);
    __shared__ float red[256];
    float mx = fmaxf(fmaxf(v.x, v.y), fmaxf(v.z, v.w));
    red[tid] = mx; __syncthreads();
    for (int off = 128; off > 0; off >>= 1) {
        if (tid < off) red[tid] = fmaxf(red[tid], red[tid + off]);
        __syncthreads();
    }
    mx = red[0]; __syncthreads();
    float e0 = expf(v.x - mx), e1 = expf(v.y - mx), e2 = expf(v.z - mx), e3 = expf(v.w - mx);
    red[tid] = e0 + e1 + e2 + e3; __syncthreads();
    for (int off = 128; off > 0; off >>= 1) {
        if (tid < off) red[tid] += red[tid + off];
        __syncthreads();
    }
    float inv = 1.f / red[0];
    u16* wp = (u16*)rp;
    wp[tid * 4 + 0] = f2b(e0 * inv);
    wp[tid * 4 + 1] = f2b(e1 * inv);
    wp[tid * 4 + 2] = f2b(e2 * inv);
    wp[tid * 4 + 3] = f2b(e3 * inv);
}

// Router: logits from f32 xn2, max + argmax per token.
__global__ __launch_bounds__(256) void router_kernel(
    const float* __restrict__ xn2, const float* __restrict__ Wg,
    const float* __restrict__ bgp, float* __restrict__ mOut, int* __restrict__ topiOut)
{
    int g = blockIdx.x;
    int tid = threadIdx.x;
    __shared__ float r0[256], r1[256];
    const float* xp = xn2 + (size_t)g * C_;
    float a0 = 0.f, a1 = 0.f;
    for (int c = tid; c < C_; c += 256) {
        float xv = xp[c];
        a0 += xv * Wg[c * 2 + 0];
        a1 += xv * Wg[c * 2 + 1];
    }
    r0[tid] = a0; r1[tid] = a1; __syncthreads();
    for (int off = 128; off > 0; off >>= 1) {
        if (tid < off) { r0[tid] += r0[tid + off]; r1[tid] += r1[tid + off]; }
        __syncthreads();
    }
    if (tid == 0) {
        float l0 = r0[0] + bgp[0];
        float l1 = r1[0] + bgp[1];
        topiOut[g] = (l1 > l0) ? 1 : 0;
        mOut[g] = fmaxf(l0, l1);
    }
}

// Softmax of max-logit over TOKEN axis (faithful bug) -> per-expert coef.
__global__ __launch_bounds__(256) void gatecoef_kernel(
    const float* __restrict__ m, const int* __restrict__ topi, float* __restrict__ coef)
{
    int b = blockIdx.x;
    int tid = threadIdx.x;
    __shared__ float red[256];
    const float* mp = m + (size_t)b * T_;
    float mx = -INFINITY;
    for (int t = tid; t < T_; t += 256) mx = fmaxf(mx, mp[t]);
    red[tid] = mx; __syncthreads();
    for (int off = 128; off > 0; off >>= 1) {
        if (tid < off) red[tid] = fmaxf(red[tid], red[tid + off]);
        __syncthreads();
    }
    mx = red[0]; __syncthreads();
    float s = 0.f;
    for (int t = tid; t < T_; t += 256) s += expf(mp[t] - mx);
    red[tid] = s; __syncthreads();
    for (int off = 128; off > 0; off >>= 1) {
        if (tid < off) red[tid] += red[tid + off];
        __syncthreads();
    }
    float inv = 1.f / red[0];
    for (int t = tid; t < T_; t += 256) {
        int g = b * T_ + t;
        float wv = expf(mp[t] - mx) * inv;
        int e = topi[g];
        coef[g]       = (e == 0) ? wv : 0.f;
        coef[BT_ + g] = (e == 1) ? wv : 0.f;
    }
}

// ============================================================================
// Host
// ============================================================================
extern "C" void kernel_launch(void* const* d_in, const int* in_sizes, int n_in,
                              void* d_out, int out_size, void* d_ws, size_t ws_size,
                              hipStream_t stream)
{
    const float* x    = (const float*)d_in[0];
    const float* Wq   = (const float*)d_in[1];
    const float* Wk   = (const float*)d_in[2];
    const float* Wv   = (const float*)d_in[3];
    const float* Wp   = (const float*)d_in[4];
    const float* bp   = (const float*)d_in[5];
    const float* ln1g = (const float*)d_in[6];
    const float* ln1b = (const float*)d_in[7];
    const float* ln2g = (const float*)d_in[8];
    const float* ln2b = (const float*)d_in[9];
    const float* Wg   = (const float*)d_in[10];
    const float* bg   = (const float*)d_in[11];
    const float* Ew1  = (const float*)d_in[12];
    const float* Eb1  = (const float*)d_in[13];
    const float* Ews  = (const float*)d_in[14];
    const float* Ebs  = (const float*)d_in[15];
    const float* Ebeta= (const float*)d_in[16];
    const float* Ewg  = (const float*)d_in[17];
    const float* Ebg  = (const float*)d_in[18];
    const float* Ew2  = (const float*)d_in[19];
    const float* Eb2  = (const float*)d_in[20];
    float* out = (float*)d_out;

    char* ws = (char*)d_ws;
    const size_t MB = 1024 * 1024;
    // Phase-A layout (offsets in bytes); phase-B aliases dead regions.
    u16*  xnbf   = (u16*) (ws + 0);        // 4 MB   (later: xn2bf)
    u16*  WqsT   = (u16*) (ws + 4*MB);     // 2 MB
    u16*  WkT    = (u16*) (ws + 6*MB);     // 2 MB
    u16*  WvT    = (u16*) (ws + 8*MB);     // 2 MB
    u16*  WpT    = (u16*) (ws + 10*MB);    // 2 MB
    u16*  Qbf    = (u16*) (ws + 12*MB);    // 4 MB   (MoE: p 12-28)
    u16*  Kbf    = (u16*) (ws + 16*MB);    // 4 MB
    u16*  Vbf    = (u16*) (ws + 20*MB);    // 4 MB
    u16*  KrT    = (u16*) (ws + 24*MB);    // 4 MB
    u16*  VT     = (u16*) (ws + 28*MB);    // 4 MB   (later: xn2f 28-36)
    u16*  Obf    = (u16*) (ws + 32*MB);    // 4 MB
    float* x1    = (float*)(ws + 36*MB);   // 8 MB
    float* sc    = (float*)(ws + 44*MB);   // 16.78 MB scores chunk (MoE: h1 44-60)
    float* mbuf  = (float*)(ws + 61*MB);   // 8 KB
    int*   topi  = (int*)  (ws + 61*MB + 16*1024);
    float* coef  = (float*)(ws + 61*MB + 32*1024);  // [2][2048]
    // Phase-B aliases
    u16*  xn2bf  = (u16*) (ws + 0);
    float* xn2f  = (float*)(ws + 28*MB);
    u16*  h1     = (u16*) (ws + 44*MB);    // 16 MB [2048][4096]
    u16*  pbuf   = (u16*) (ws + 12*MB);    // 16 MB [2048][4096]

    // --- 1. LN1 -> bf16 ---
    ln_kernel<<<BT_, 256, 0, stream>>>(x, ln1g, ln1b, xnbf, nullptr, 0);

    // --- 2. weight prep ---
    prep_whcd<<<C_*C_/256, 256, 0, stream>>>(Wk, WkT);
    prep_whcd<<<C_*C_/256, 256, 0, stream>>>(Wv, WvT);
    prep_wq  <<<C_*C_/256, 256, 0, stream>>>(Wq, WqsT);
    prep_wp  <<<C_*C_/256, 256, 0, stream>>>(Wp, WpT);

    // --- 3. Q/K/V projections (TN, bf16 out) ---
    {
        dim3 grid(16, 16, 1);
        gemm_tn<2,1><<<grid, 256, 0, stream>>>(xnbf, WqsT, nullptr, Qbf, nullptr, nullptr,
            C_, C_, C_, C_, 0, 0,0,0, 0,0, 0,0,0);
        gemm_tn<2,1><<<grid, 256, 0, stream>>>(xnbf, WkT, nullptr, Kbf, nullptr, nullptr,
            C_, C_, C_, C_, 0, 0,0,0, 0,0, 0,0,0);
        gemm_tn<2,1><<<grid, 256, 0, stream>>>(xnbf, WvT, nullptr, Vbf, nullptr, nullptr,
            C_, C_, C_, C_, 0, 0,0,0, 0,0, 0,0,0);
    }
    prep_krt<<<H_*B_*T_*64/256, 256, 0, stream>>>(Kbf, KrT);
    prep_vt <<<H_*B_*T_*64/256, 256, 0, stream>>>(Vbf, VT);

    // --- 4. attention in hb-chunks of G_ ---
    for (int chunk = 0; chunk < (H_*B_)/G_; ++chunk) {
        int hb0 = chunk * G_;
        // scores = Q·KrT^T * 0.125, window mask; f32 [G][1024][1024]
        gemm_tn<4,2><<<dim3(8, 8, G_), 256, 0, stream>>>(
            Qbf, KrT, sc, nullptr, nullptr, nullptr,
            64, C_, 64, 1024, hb0,
            /*aCz*/0, /*aCb*/1048576, /*aCh*/64,
            /*bCb*/65536, /*bCh*/131072,
            /*cCz*/1048576, 0, 0);
        // softmax rows, in-place -> bf16
        softmax_rows<<<G_*1024, 256, 0, stream>>>(sc);
        // O = W·VT^T -> Obf[b*T+t][h*64+d]
        gemm_tn<2,1><<<dim3(1, 8, G_), 256, 0, stream>>>(
            (u16*)sc, VT, nullptr, Obf, nullptr, nullptr,
            1024, 2048, 1024, 1024, hb0,
            /*aCz*/2097152, 0, 0,
            /*bCb*/65536, /*bCh*/131072,
            /*cCz*/0, /*cCb*/1048576, /*cCh*/64);
    }

    // --- 5. x1 = x + Obf@WpT + bp ---
    gemm_tn<2,3><<<dim3(16, 16, 1), 256, 0, stream>>>(
        Obf, WpT, x1, nullptr, bp, x,
        C_, C_, C_, C_, 0, 0,0,0, 0,0, 0,0,0);

    // --- 6. LN2 (f32 for router + bf16 for GEMMs) ---
    ln_kernel<<<BT_, 256, 0, stream>>>(x1, ln2g, ln2b, xn2bf, xn2f, 1);

    // --- 7. router + gate ---
    router_kernel<<<BT_, 256, 0, stream>>>(xn2f, Wg, bg, mbuf, topi);
    gatecoef_kernel<<<B_, 256, 0, stream>>>(mbuf, topi, coef);

    // --- 8. MoE, dense per expert, full M=2048 ---
    for (int e = 0; e < E_; ++e) {
        // h1 = xn2@Ew1[e] + Eb1[e] -> bf16 [2048][4096]
        gemm_nt<4,0><<<dim3(32, 16), 256, 0, stream>>>(
            xn2bf, Ew1 + (size_t)e * C_ * NH_, h1, nullptr,
            Eb1 + (size_t)e * NH_, nullptr, nullptr,
            C_, C_, NH_, NH_);
        // p = swish(h1@Ews+Ebs) * (h1@Ewg+Ebg) -> bf16
        gemm_nt_dual<<<dim3(64, 16), 256, 0, stream>>>(
            h1, Ews + (size_t)e * NH_ * NH_, Ewg + (size_t)e * NH_ * NH_,
            Ebs + (size_t)e * NH_, Ebg + (size_t)e * NH_, Ebeta + e,
            pbuf, NH_, NH_, NH_, NH_);
        // out (+)= coef_e * (p@Ew2[e] + Eb2[e])  (+ x1 on first pass)
        if (e == 0)
            gemm_nt<2,1><<<dim3(16, 16), 256, 0, stream>>>(
                pbuf, Ew2 + (size_t)e * NH_ * C_, nullptr, out,
                Eb2 + (size_t)e * C_, coef + e * BT_, x1,
                NH_, NH_, C_, C_);
        else
            gemm_nt<2,2><<<dim3(16, 16), 256, 0, stream>>>(
                pbuf, Ew2 + (size_t)e * NH_ * C_, nullptr, out,
                Eb2 + (size_t)e * C_, coef + e * BT_, nullptr,
                NH_, NH_, C_, C_);
    }
}